// Round 1
// baseline (78.340 us; speedup 1.0000x reference)
//
#include <hip/hip_runtime.h>
#include <stdint.h>

#define OUTD 4000
#define NPAD 4096
#define CC 16
#define WW 48
#define HH 48
#define BB 128
#define KD 768          // C*H contraction
#define MD 6144         // B*W rows
#define EPSF 1e-6f

#define BM 96
#define BN 128
#define BK 64

using short8 = __attribute__((ext_vector_type(8))) short;
using f32x4  = __attribute__((ext_vector_type(4))) float;

__device__ __forceinline__ unsigned short f2bf(float f) {
  union { float f; unsigned int u; } v; v.f = f;
  unsigned int u = v.u;
  unsigned int r = (u + 0x7FFFu + ((u >> 16) & 1u)) >> 16;
  return (unsigned short)r;
}

// ---------------- Kernel 0: normalize weights, build Qt[n][c*48+h] (bf16) and wnT[w][n] (f32)
__global__ void prep_weights(const float* __restrict__ width,
                             const float* __restrict__ height,
                             const float* __restrict__ feat,
                             unsigned short* __restrict__ Qt,
                             float* __restrict__ wnT) {
  int n = blockIdx.x;          // 0..4095
  int lane = threadIdx.x;      // 64
  bool valid = (n < OUTD);
  float hv = (valid && lane < HH) ? height[n * HH + lane] : 0.f;
  float wv = (valid && lane < WW) ? width[n * WW + lane] : 0.f;
  float hs = hv * hv, wsum = wv * wv;
  #pragma unroll
  for (int off = 32; off > 0; off >>= 1) {
    hs += __shfl_xor(hs, off);
    wsum += __shfl_xor(wsum, off);
  }
  float hnorm = rsqrtf(hs + EPSF);
  float wnorm = rsqrtf(wsum + EPSF);
  if (lane < WW) wnT[lane * NPAD + n] = valid ? width[n * WW + lane] * wnorm : 0.f;
  if (valid) {
    for (int i = lane; i < KD; i += 64) {
      int c = i / HH, h = i % HH;
      Qt[(size_t)n * KD + i] = f2bf(feat[n * CC + c] * height[n * HH + h] * hnorm);
    }
  } else {
    for (int i = lane; i < KD; i += 64) Qt[(size_t)n * KD + i] = 0;
  }
}

// ---------------- Kernel 1: x[b,c,w,h] f32 -> A[(b*48+w)][c*48+h] bf16
__global__ void prep_x(const float* __restrict__ x, unsigned short* __restrict__ A) {
  int i = blockIdx.x * blockDim.x + threadIdx.x;
  if (i >= BB * CC * WW * HH) return;
  int h = i % HH;
  int w = (i / HH) % WW;
  int c = (i / (HH * WW)) % CC;
  int b = i / (HH * WW * CC);
  A[(size_t)(b * WW + w) * KD + c * HH + h] = f2bf(x[i]);
}

// ---------------- Main GEMM: P = A (6144x768) * Qt^T (768x4096), fused w-reduction epilogue
__global__ __launch_bounds__(256)
void gemm_main(const unsigned short* __restrict__ A,   // [6144][768] bf16 bits
               const unsigned short* __restrict__ Qt,  // [4096][768] bf16 bits
               const float* __restrict__ wnT,          // [48][4096]
               const float* __restrict__ bias,         // [4000]
               float* __restrict__ out) {              // [128][4000]
  __shared__ unsigned short As[BM * BK];   // [96][64]
  __shared__ unsigned short Bs[BN * BK];   // [128][64]  (row = n_local, col = k)

  int tid = threadIdx.x;
  int lane = tid & 63;
  int wid = tid >> 6;
  int wm = wid >> 1;     // 0..1 -> which batch within tile
  int wn = wid & 1;      // 0..1 -> which 64-col half
  int bx = blockIdx.x;   // n tile (32)
  int by = blockIdx.y;   // m tile (64)
  int n0 = bx * BN;
  int m0 = by * BM;

  f32x4 acc[3][4] = {};

  int rsub = lane >> 3;          // 0..7 : row within 8-row staging chunk
  int ksub = (lane & 7) * 8;     // element offset within 64-wide k row

  const unsigned short* gA = A + (size_t)m0 * KD;
  const unsigned short* gB = Qt + (size_t)n0 * KD;

  for (int ks = 0; ks < KD / BK; ++ks) {
    int k0 = ks * BK;
    #pragma unroll
    for (int j3 = 0; j3 < 3; ++j3) {           // A: 12 chunks of 8 rows, 3 per wave
      int j = wid * 3 + j3;
      int row = j * 8 + rsub;
      __builtin_amdgcn_global_load_lds(
          (const __attribute__((address_space(1))) void*)(gA + (size_t)row * KD + k0 + ksub),
          (__attribute__((address_space(3))) void*)(&As[j * 512]),
          16, 0, 0);
    }
    #pragma unroll
    for (int j4 = 0; j4 < 4; ++j4) {           // B: 16 chunks, 4 per wave
      int j = wid * 4 + j4;
      int row = j * 8 + rsub;
      __builtin_amdgcn_global_load_lds(
          (const __attribute__((address_space(1))) void*)(gB + (size_t)row * KD + k0 + ksub),
          (__attribute__((address_space(3))) void*)(&Bs[j * 512]),
          16, 0, 0);
    }
    __syncthreads();   // drains vmcnt -> tiles ready

    #pragma unroll
    for (int kc = 0; kc < 2; ++kc) {
      short8 af[3], bfv[4];
      int kof = kc * 32 + (lane >> 4) * 8;
      #pragma unroll
      for (int mi = 0; mi < 3; ++mi)
        af[mi] = *(const short8*)&As[(wm * 48 + mi * 16 + (lane & 15)) * BK + kof];
      #pragma unroll
      for (int ni = 0; ni < 4; ++ni)
        bfv[ni] = *(const short8*)&Bs[(wn * 64 + ni * 16 + (lane & 15)) * BK + kof];
      #pragma unroll
      for (int mi = 0; mi < 3; ++mi)
        #pragma unroll
        for (int ni = 0; ni < 4; ++ni)
          acc[mi][ni] = __builtin_amdgcn_mfma_f32_16x16x32_bf16(af[mi], bfv[ni], acc[mi][ni], 0, 0, 0);
    }
    __syncthreads();
  }

  // Epilogue: rows of this wave's tile are w = mi*16 + rg*4 + r for batch b = by*2 + wm.
  // y[b, n] = sum_w wnT[w][n] * P[w][n] + bias[n]
  int col = lane & 15;
  int rg = lane >> 4;
  int b = by * 2 + wm;
  #pragma unroll
  for (int ni = 0; ni < 4; ++ni) {
    int ng = n0 + wn * 64 + ni * 16 + col;
    float sum = 0.f;
    #pragma unroll
    for (int mi = 0; mi < 3; ++mi) {
      int wbase = mi * 16 + rg * 4;
      f32x4 v = acc[mi][ni];
      #pragma unroll
      for (int r = 0; r < 4; ++r)
        sum += wnT[(wbase + r) * NPAD + ng] * v[r];
    }
    sum += __shfl_xor(sum, 16);
    sum += __shfl_xor(sum, 32);
    if (rg == 0 && ng < OUTD)
      out[(size_t)b * OUTD + ng] = sum + bias[ng];
  }
}

extern "C" void kernel_launch(void* const* d_in, const int* in_sizes, int n_in,
                              void* d_out, int out_size, void* d_ws, size_t ws_size,
                              hipStream_t stream) {
  const float* x      = (const float*)d_in[0];
  const float* width  = (const float*)d_in[1];
  const float* height = (const float*)d_in[2];
  const float* feat   = (const float*)d_in[3];
  const float* bias   = (const float*)d_in[4];
  float* out = (float*)d_out;

  char* ws = (char*)d_ws;
  unsigned short* A  = (unsigned short*)ws;                        // 6144*768*2 = 9,437,184
  unsigned short* Qt = (unsigned short*)(ws + 9437184);            // 4096*768*2 = 6,291,456
  float* wnT         = (float*)(ws + 9437184 + 6291456);           // 48*4096*4  =   786,432

  prep_weights<<<dim3(NPAD), dim3(64), 0, stream>>>(width, height, feat, Qt, wnT);
  int total = BB * CC * WW * HH;
  prep_x<<<dim3((total + 255) / 256), dim3(256), 0, stream>>>(x, A);
  gemm_main<<<dim3(BN == 128 ? NPAD / BN : 32, MD / BM), dim3(256), 0, stream>>>(A, Qt, wnT, bias, out);
}

// Round 2
// 66.037 us; speedup vs baseline: 1.1863x; 1.1863x over previous
//
#include <hip/hip_runtime.h>
#include <stdint.h>

#define OUTD 4000
#define NPAD 4096
#define CC 16
#define WW 48
#define HH 48
#define BB 128
#define KD 768          // C*H contraction depth
#define MD 6144         // B*W rows
#define EPSF 1e-6f

#define BM 192          // 4 batches * 48 w
#define BN 128
#define BK 64
#define KSTEPS 12
#define ACH 24          // A chunks of 1KB per K-step
#define THREADS 512

using short8 = __attribute__((ext_vector_type(8))) short;
using f32x4  = __attribute__((ext_vector_type(4))) float;

static __device__ __forceinline__ unsigned short f2bf(float f) {
  union { float f; unsigned int u; } v; v.f = f;
  unsigned int u = v.u;
  unsigned int r = (u + 0x7FFFu + ((u >> 16) & 1u)) >> 16;
  return (unsigned short)r;
}

// ---------------- Kernel 0: normalize weights, build Qt[n][c*48+h] (bf16) and wnT[w][n] (f32)
__global__ void prep_weights(const float* __restrict__ width,
                             const float* __restrict__ height,
                             const float* __restrict__ feat,
                             unsigned short* __restrict__ Qt,
                             float* __restrict__ wnT) {
  int n = blockIdx.x;          // 0..4095
  int lane = threadIdx.x;      // 64
  bool valid = (n < OUTD);
  float hv = (valid && lane < HH) ? height[n * HH + lane] : 0.f;
  float wv = (valid && lane < WW) ? width[n * WW + lane] : 0.f;
  float hs = hv * hv, wsum = wv * wv;
  #pragma unroll
  for (int off = 32; off > 0; off >>= 1) {
    hs += __shfl_xor(hs, off);
    wsum += __shfl_xor(wsum, off);
  }
  float hnorm = rsqrtf(hs + EPSF);
  float wnorm = rsqrtf(wsum + EPSF);
  if (lane < WW) wnT[lane * NPAD + n] = valid ? width[n * WW + lane] * wnorm : 0.f;
  if (valid) {
    for (int i = lane; i < KD; i += 64) {
      int c = i / HH, h = i % HH;
      Qt[(size_t)n * KD + i] = f2bf(feat[n * CC + c] * height[n * HH + h] * hnorm);
    }
  } else {
    for (int i = lane; i < KD; i += 64) Qt[(size_t)n * KD + i] = 0;
  }
}

// ---------------- Kernel 1: x[b,c,w,h] f32 -> A[(b*48+w)][c*48+h] bf16, 8 elems/thread
__global__ void prep_x8(const float* __restrict__ x, unsigned short* __restrict__ A) {
  int t = blockIdx.x * blockDim.x + threadIdx.x;
  if (t >= BB * CC * WW * HH / 8) return;
  int e = t * 8;
  int h0 = e % HH;                  // 8 | 48, so the 8 elems share (b,c,w)
  int w = (e / HH) % WW;
  int c = (e / (HH * WW)) % CC;
  int b = e / (HH * WW * CC);
  const float4* src = (const float4*)(x + e);
  float4 v0 = src[0];
  float4 v1 = src[1];
  short8 o;
  o[0] = (short)f2bf(v0.x); o[1] = (short)f2bf(v0.y);
  o[2] = (short)f2bf(v0.z); o[3] = (short)f2bf(v0.w);
  o[4] = (short)f2bf(v1.x); o[5] = (short)f2bf(v1.y);
  o[6] = (short)f2bf(v1.z); o[7] = (short)f2bf(v1.w);
  *(short8*)&A[(size_t)(b * WW + w) * KD + c * HH + h0] = o;
}

// ---------------- Main GEMM: P = A (6144x768) * Qt^T (768x4096), fused w-reduction epilogue
// 192x128 tile, BK=64, 8 waves (4m x 2n), double-buffered LDS, counted vmcnt,
// XOR-swizzled staging (pre-swizzled global source + swizzled ds_read).
__global__ __launch_bounds__(THREADS, 4)
void gemm_main(const unsigned short* __restrict__ A,   // [6144][768] bf16 bits
               const unsigned short* __restrict__ Qt,  // [4096][768] bf16 bits
               const float* __restrict__ wnT,          // [48][4096]
               const float* __restrict__ bias,         // [4000]
               float* __restrict__ out) {              // [128][4000]
  // One combined LDS block: A region [192][64] then B region [128][64], x2 buffers.
  __shared__ unsigned short S[2][(BM + BN) * BK];   // 2 * 40960 B = 81920 B

  int tid = threadIdx.x;
  int lane = tid & 63;
  int wid = tid >> 6;          // 0..7
  int wm = wid >> 1;           // 0..3 -> which batch (48 rows) of the tile
  int wnh = wid & 1;           // 0..1 -> which 64-col half

  // XCD-aware block swizzle: XCD k gets bx in [k*4, k*4+4), all by.
  int bid = blockIdx.x;        // 0..1023
  int xk = bid & 7;
  int m = bid >> 3;            // 0..127
  int bx = xk * 4 + (m >> 5);  // n tile 0..31
  int by = m & 31;             // m tile 0..31
  int n0 = bx * BN;
  int m0 = by * BM;

  // ---- staging setup: 40 chunks of 1KB (8 rows x 64 elems), 5 per wave.
  // LDS dest is linear; global source column is XOR-pre-swizzled so that
  // LDS[row][cb*8..] holds global[row][(cb ^ (row&7))*8..].
  int rsub = lane >> 3;
  int kswb = ((lane & 7) ^ rsub) * 8;   // swizzled column (elems) for this lane
  const unsigned short* gsrc[5];
  #pragma unroll
  for (int j = 0; j < 5; ++j) {
    int q = wid * 5 + j;
    if (q < ACH) gsrc[j] = A  + (size_t)(m0 + q * 8 + rsub) * KD + kswb;
    else         gsrc[j] = Qt + (size_t)(n0 + (q - ACH) * 8 + rsub) * KD + kswb;
  }

#define STAGE(ks, buf)                                                          \
  {                                                                             \
    _Pragma("unroll")                                                           \
    for (int j = 0; j < 5; ++j) {                                               \
      __builtin_amdgcn_global_load_lds(                                         \
          (const __attribute__((address_space(1))) void*)(gsrc[j] + (ks) * BK), \
          (__attribute__((address_space(3))) void*)(&S[buf][(wid * 5 + j) * 512]), \
          16, 0, 0);                                                            \
    }                                                                           \
  }

  // ---- ds_read bases (elem offsets into S[buf]) with matching XOR swizzle
  int q16 = lane & 15;
  int hi = lane >> 4;          // 0..3
  int q7 = q16 & 7;
  int aofs0 = (wm * 48 + q16) * BK + (((0 + hi) ^ q7) * 8);   // kc=0
  int aofs1 = (wm * 48 + q16) * BK + (((4 + hi) ^ q7) * 8);   // kc=1
  int bofs0 = BM * BK + (wnh * 64 + q16) * BK + (((0 + hi) ^ q7) * 8);
  int bofs1 = BM * BK + (wnh * 64 + q16) * BK + (((4 + hi) ^ q7) * 8);

  f32x4 acc[3][4] = {};

  STAGE(0, 0);   // prologue: stage K-step 0 into buffer 0

  #pragma unroll
  for (int ks = 0; ks < KSTEPS; ++ks) {
    const int buf = ks & 1;
    if (ks + 1 < KSTEPS) {
      STAGE(ks + 1, buf ^ 1);                       // prefetch next step
      asm volatile("s_waitcnt vmcnt(5)" ::: "memory");   // current step's 5 loads done
    } else {
      asm volatile("s_waitcnt vmcnt(0)" ::: "memory");
    }
    __builtin_amdgcn_s_barrier();
    __builtin_amdgcn_sched_barrier(0);

    const unsigned short* sb = &S[buf][0];
    #pragma unroll
    for (int kc = 0; kc < 2; ++kc) {
      short8 af[3], bfv[4];
      int ab = kc ? aofs1 : aofs0;
      int bb = kc ? bofs1 : bofs0;
      #pragma unroll
      for (int mi = 0; mi < 3; ++mi)
        af[mi] = *(const short8*)&sb[ab + mi * 16 * BK];
      #pragma unroll
      for (int ni = 0; ni < 4; ++ni)
        bfv[ni] = *(const short8*)&sb[bb + ni * 16 * BK];
      __builtin_amdgcn_s_setprio(1);
      #pragma unroll
      for (int mi = 0; mi < 3; ++mi)
        #pragma unroll
        for (int ni = 0; ni < 4; ++ni)
          acc[mi][ni] = __builtin_amdgcn_mfma_f32_16x16x32_bf16(af[mi], bfv[ni], acc[mi][ni], 0, 0, 0);
      __builtin_amdgcn_s_setprio(0);
    }

    __builtin_amdgcn_s_barrier();   // protect buf[(ks+1)&1] before next prefetch overwrites
    __builtin_amdgcn_sched_barrier(0);
  }

  // ---- Epilogue: y[b,n] = sum_w wnT[w][n] * P[(b,w),n] + bias[n]
  // wave rows: w = mi*16 + hi*4 + r, batch b = by*4 + wm.
  int b = by * 4 + wm;
  #pragma unroll
  for (int ni = 0; ni < 4; ++ni) {
    int ng = n0 + wnh * 64 + ni * 16 + q16;
    float sum = 0.f;
    #pragma unroll
    for (int mi = 0; mi < 3; ++mi) {
      int wbase = mi * 16 + hi * 4;
      f32x4 v = acc[mi][ni];
      #pragma unroll
      for (int r = 0; r < 4; ++r)
        sum += wnT[(wbase + r) * NPAD + ng] * v[r];
    }
    sum += __shfl_xor(sum, 16);
    sum += __shfl_xor(sum, 32);
    if (hi == 0 && ng < OUTD)
      out[(size_t)b * OUTD + ng] = sum + bias[ng];
  }
#undef STAGE
}

extern "C" void kernel_launch(void* const* d_in, const int* in_sizes, int n_in,
                              void* d_out, int out_size, void* d_ws, size_t ws_size,
                              hipStream_t stream) {
  const float* x      = (const float*)d_in[0];
  const float* width  = (const float*)d_in[1];
  const float* height = (const float*)d_in[2];
  const float* feat   = (const float*)d_in[3];
  const float* bias   = (const float*)d_in[4];
  float* out = (float*)d_out;

  char* ws = (char*)d_ws;
  unsigned short* A  = (unsigned short*)ws;                        // 6144*768*2 = 9,437,184
  unsigned short* Qt = (unsigned short*)(ws + 9437184);            // 4096*768*2 = 6,291,456
  float* wnT         = (float*)(ws + 9437184 + 6291456);           // 48*4096*4  =   786,432

  prep_weights<<<dim3(NPAD), dim3(64), 0, stream>>>(width, height, feat, Qt, wnT);
  int t8 = BB * CC * WW * HH / 8;
  prep_x8<<<dim3((t8 + 255) / 256), dim3(256), 0, stream>>>(x, A);
  gemm_main<<<dim3(1024), dim3(THREADS), 0, stream>>>(A, Qt, wnT, bias, out);
}

// Round 3
// 59.593 us; speedup vs baseline: 1.3146x; 1.1081x over previous
//
#include <hip/hip_runtime.h>
#include <stdint.h>

#define OUTD 4000
#define NPAD 4096
#define CC 16
#define WW 48
#define HH 48
#define BB 128
#define KD 768          // C*H contraction depth
#define MD 6144         // B*W rows
#define EPSF 1e-6f

#define BM 192          // 4 batches * 48 w
#define BN 128
#define BK 64
#define KSTEPS 12
#define THREADS 512
#define XPB 2304        // blocks for x-conversion in prep_all

using short8 = __attribute__((ext_vector_type(8))) short;
using f32x4  = __attribute__((ext_vector_type(4))) float;

static __device__ __forceinline__ unsigned short f2bf(float f) {
  union { float f; unsigned int u; } v; v.f = f;
  unsigned int u = v.u;
  unsigned int r = (u + 0x7FFFu + ((u >> 16) & 1u)) >> 16;
  return (unsigned short)r;
}

// ---------------- Fused prep: blocks [0,XPB) convert x -> A (bf16, merged (c,h) K axis);
// blocks [XPB, XPB+1024) normalize weights -> Qt (bf16) + wnT (f32, [48][4096]).
__global__ __launch_bounds__(256)
void prep_all(const float* __restrict__ x,
              const float* __restrict__ width,
              const float* __restrict__ height,
              const float* __restrict__ feat,
              unsigned short* __restrict__ A,
              unsigned short* __restrict__ Qt,
              float* __restrict__ wnT) {
  __shared__ float smw[4][WW];
  int bid = blockIdx.x;
  if (bid < XPB) {
    int t = bid * 256 + threadIdx.x;      // XPB*256 == BB*CC*WW*HH/8 exactly
    int e = t * 8;
    int h0 = e % HH;                      // 8 | 48: the 8 elems share (b,c,w)
    int w = (e / HH) % WW;
    int c = (e / (HH * WW)) % CC;
    int b = e / (HH * WW * CC);
    float4 v0 = *(const float4*)(x + e);
    float4 v1 = *(const float4*)(x + e + 4);
    short8 o;
    o[0] = (short)f2bf(v0.x); o[1] = (short)f2bf(v0.y);
    o[2] = (short)f2bf(v0.z); o[3] = (short)f2bf(v0.w);
    o[4] = (short)f2bf(v1.x); o[5] = (short)f2bf(v1.y);
    o[6] = (short)f2bf(v1.z); o[7] = (short)f2bf(v1.w);
    *(short8*)&A[(size_t)(b * WW + w) * KD + c * HH + h0] = o;
  } else {
    int lane = threadIdx.x & 63;
    int wv = threadIdx.x >> 6;            // wave 0..3
    int nbase = (bid - XPB) * 4;
    int n = nbase + wv;                   // 0..4095
    bool valid = (n < OUTD);
    float hv = (valid && lane < HH) ? height[n * HH + lane] : 0.f;
    float wvv = (valid && lane < WW) ? width[n * WW + lane] : 0.f;
    float hs = hv * hv, wsum = wvv * wvv;
    #pragma unroll
    for (int off = 32; off > 0; off >>= 1) {
      hs += __shfl_xor(hs, off);
      wsum += __shfl_xor(wsum, off);
    }
    float hnorm = rsqrtf(hs + EPSF);
    float wnorm = rsqrtf(wsum + EPSF);
    if (lane < WW) smw[wv][lane] = wvv * wnorm;   // 0 for invalid n
    if (valid) {
      #pragma unroll
      for (int i = lane; i < KD; i += 64) {
        int c = i / HH, h = i % HH;
        Qt[(size_t)n * KD + i] = f2bf(feat[n * CC + c] * height[n * HH + h] * hnorm);
      }
    } else {
      #pragma unroll
      for (int i = lane; i < KD; i += 64) Qt[(size_t)n * KD + i] = 0;
    }
    __syncthreads();
    if (threadIdx.x < WW) {
      int w = threadIdx.x;
      float4 o = make_float4(smw[0][w], smw[1][w], smw[2][w], smw[3][w]);
      *(float4*)&wnT[w * NPAD + nbase] = o;
    }
  }
}

// ---------------- Main GEMM: P = A (6144x768) * Qt^T (768x4096), fused w-reduction epilogue.
// 192x128 tile, BK=64, 8 waves (4m x 2n). 3-deep LDS ring, counted vmcnt (never 0 in-loop),
// 4 phases per K-step with barrier-paced MFMA clusters, XOR-swizzled staging.
__global__ __launch_bounds__(THREADS, 2)
void gemm_main(const unsigned short* __restrict__ A,   // [6144][768] bf16 bits
               const unsigned short* __restrict__ Qt,  // [4096][768] bf16 bits
               const float* __restrict__ wnT,          // [48][4096]
               const float* __restrict__ bias,         // [4000]
               float* __restrict__ out) {              // [128][4000]
  // Ring of 3 buffers: A region [192][64] then B region [128][64] per buffer.
  __shared__ unsigned short S[3][(BM + BN) * BK];   // 3 * 40960 B = 122880 B -> 1 block/CU

  int tid = threadIdx.x;
  int lane = tid & 63;
  int wid = tid >> 6;          // 0..7
  int wm = wid >> 1;           // 0..3 -> which batch (48 rows) of the tile
  int wnh = wid & 1;           // 0..1 -> which 64-col half

  // XCD-local mapping: XCD k (= bid&7) owns by in [4k, 4k+4), sweeps bx.
  // A-share per XCD = 4*294KB = 1.2MB (L2-resident); Qt streams once per XCD.
  int bid = blockIdx.x;        // 0..1023
  int xcd = bid & 7;
  int idx = bid >> 3;          // 0..127
  int by = xcd * 4 + (idx & 3);   // m tile 0..31
  int bx = idx >> 2;              // n tile 0..31
  int n0 = bx * BN;
  int m0 = by * BM;

  // ---- staging: per wave 3 A-chunks + 2 B-chunks of 1KB (8 rows x 64 elems).
  // LDS dest linear; global source column XOR-pre-swizzled: LDS[row][cb*8..]
  // holds global[row][(cb ^ (row&7))*8..].
  int rsub = lane >> 3;
  int kswb = ((lane & 7) ^ rsub) * 8;
  const unsigned short* gA[3];
  const unsigned short* gB[2];
  #pragma unroll
  for (int j = 0; j < 3; ++j)
    gA[j] = A + (size_t)(m0 + (wid * 3 + j) * 8 + rsub) * KD + kswb;
  #pragma unroll
  for (int j = 0; j < 2; ++j)
    gB[j] = Qt + (size_t)(n0 + (wid * 2 + j) * 8 + rsub) * KD + kswb;

#define STAGE_A(ks, buf)                                                         \
  { _Pragma("unroll")                                                            \
    for (int j = 0; j < 3; ++j)                                                  \
      __builtin_amdgcn_global_load_lds(                                          \
          (const __attribute__((address_space(1))) void*)(gA[j] + (ks) * BK),    \
          (__attribute__((address_space(3))) void*)(&S[buf][(wid * 3 + j) * 512]), \
          16, 0, 0); }
#define STAGE_B(ks, buf)                                                         \
  { _Pragma("unroll")                                                            \
    for (int j = 0; j < 2; ++j)                                                  \
      __builtin_amdgcn_global_load_lds(                                          \
          (const __attribute__((address_space(1))) void*)(gB[j] + (ks) * BK),    \
          (__attribute__((address_space(3))) void*)(&S[buf][BM * BK + (wid * 2 + j) * 512]), \
          16, 0, 0); }

  // ---- ds_read bases (elem offsets) with matching XOR swizzle
  int q16 = lane & 15;
  int hi = lane >> 4;          // 0..3
  int q7 = q16 & 7;
  int aofs[2], bofs[2];
  #pragma unroll
  for (int kc = 0; kc < 2; ++kc) {
    aofs[kc] = (wm * 48 + q16) * BK + (((kc * 4 + hi) ^ q7) * 8);
    bofs[kc] = BM * BK + (wnh * 64 + q16) * BK + (((kc * 4 + hi) ^ q7) * 8);
  }

  f32x4 acc[3][4] = {};

  // Prologue: stage K-steps 0 and 1 (10 loads in flight), wait for step 0 only.
  STAGE_A(0, 0); STAGE_B(0, 0);
  STAGE_A(1, 1); STAGE_B(1, 1);
  asm volatile("s_waitcnt vmcnt(5)" ::: "memory");
  __builtin_amdgcn_s_barrier();
  __builtin_amdgcn_sched_barrier(0);

  #pragma unroll
  for (int ks = 0; ks < KSTEPS; ++ks) {
    const unsigned short* sb = &S[ks % 3][0];
    short8 af0, af1, af2;
    #pragma unroll
    for (int kc = 0; kc < 2; ++kc) {
      #pragma unroll
      for (int nh = 0; nh < 2; ++nh) {
        // --- phase (kc, nh): ds-reads for this 6-MFMA cluster
        if (nh == 0) {
          af0 = *(const short8*)&sb[aofs[kc]];
          af1 = *(const short8*)&sb[aofs[kc] + 16 * BK];
          af2 = *(const short8*)&sb[aofs[kc] + 32 * BK];
        }
        short8 b0 = *(const short8*)&sb[bofs[kc] + (nh * 2) * 16 * BK];
        short8 b1 = *(const short8*)&sb[bofs[kc] + (nh * 2 + 1) * 16 * BK];
        // --- stage-issue one half of K-step ks+2 (phases p0/p1 only)
        if (ks + 2 < KSTEPS) {
          if (kc == 0 && nh == 0) STAGE_A(ks + 2, (ks + 2) % 3);
          if (kc == 0 && nh == 1) STAGE_B(ks + 2, (ks + 2) % 3);
        }
        __builtin_amdgcn_s_barrier();
        asm volatile("s_waitcnt lgkmcnt(0)" ::: "memory");
        __builtin_amdgcn_sched_barrier(0);
        __builtin_amdgcn_s_setprio(1);
        acc[0][nh * 2]     = __builtin_amdgcn_mfma_f32_16x16x32_bf16(af0, b0, acc[0][nh * 2], 0, 0, 0);
        acc[1][nh * 2]     = __builtin_amdgcn_mfma_f32_16x16x32_bf16(af1, b0, acc[1][nh * 2], 0, 0, 0);
        acc[2][nh * 2]     = __builtin_amdgcn_mfma_f32_16x16x32_bf16(af2, b0, acc[2][nh * 2], 0, 0, 0);
        acc[0][nh * 2 + 1] = __builtin_amdgcn_mfma_f32_16x16x32_bf16(af0, b1, acc[0][nh * 2 + 1], 0, 0, 0);
        acc[1][nh * 2 + 1] = __builtin_amdgcn_mfma_f32_16x16x32_bf16(af1, b1, acc[1][nh * 2 + 1], 0, 0, 0);
        acc[2][nh * 2 + 1] = __builtin_amdgcn_mfma_f32_16x16x32_bf16(af2, b1, acc[2][nh * 2 + 1], 0, 0, 0);
        __builtin_amdgcn_s_setprio(0);
        // --- end-of-K-step counted wait (never 0 until the ring drains)
        if (kc == 1 && nh == 1) {
          if (ks <= KSTEPS - 3)      asm volatile("s_waitcnt vmcnt(5)" ::: "memory");
          else if (ks == KSTEPS - 2) asm volatile("s_waitcnt vmcnt(0)" ::: "memory");
        }
        __builtin_amdgcn_s_barrier();
        __builtin_amdgcn_sched_barrier(0);
      }
    }
  }

  // ---- Epilogue: y[b,n] = sum_w wnT[w][n] * P[(b,w),n] + bias[n]
  // wave rows: w = mi*16 + hi*4 + r, batch b = by*4 + wm.
  int b = by * 4 + wm;
  #pragma unroll
  for (int ni = 0; ni < 4; ++ni) {
    int ng = n0 + wnh * 64 + ni * 16 + q16;
    float sum = 0.f;
    #pragma unroll
    for (int mi = 0; mi < 3; ++mi) {
      int wbase = mi * 16 + hi * 4;
      f32x4 v = acc[mi][ni];
      #pragma unroll
      for (int r = 0; r < 4; ++r)
        sum += wnT[(wbase + r) * NPAD + ng] * v[r];
    }
    sum += __shfl_xor(sum, 16);
    sum += __shfl_xor(sum, 32);
    if (hi == 0 && ng < OUTD)
      out[(size_t)b * OUTD + ng] = sum + bias[ng];
  }
#undef STAGE_A
#undef STAGE_B
}

extern "C" void kernel_launch(void* const* d_in, const int* in_sizes, int n_in,
                              void* d_out, int out_size, void* d_ws, size_t ws_size,
                              hipStream_t stream) {
  const float* x      = (const float*)d_in[0];
  const float* width  = (const float*)d_in[1];
  const float* height = (const float*)d_in[2];
  const float* feat   = (const float*)d_in[3];
  const float* bias   = (const float*)d_in[4];
  float* out = (float*)d_out;

  char* ws = (char*)d_ws;
  unsigned short* A  = (unsigned short*)ws;                        // 6144*768*2 = 9,437,184
  unsigned short* Qt = (unsigned short*)(ws + 9437184);            // 4096*768*2 = 6,291,456
  float* wnT         = (float*)(ws + 9437184 + 6291456);           // 48*4096*4  =   786,432

  prep_all<<<dim3(XPB + NPAD / 4), dim3(256), 0, stream>>>(x, width, height, feat, A, Qt, wnT);
  gemm_main<<<dim3(1024), dim3(THREADS), 0, stream>>>(A, Qt, wnT, bias, out);
}

// Round 4
// 56.892 us; speedup vs baseline: 1.3770x; 1.0475x over previous
//
#include <hip/hip_runtime.h>
#include <stdint.h>

#define OUTD 4000
#define NPAD 4096
#define CC 16
#define WW 48
#define HH 48
#define BB 128
#define KD 768          // C*H contraction depth
#define MD 6144         // B*W rows
#define EPSF 1e-6f

#define BM 384          // 8 batches * 48 w
#define BN 128
#define BKU 32          // K elems per pipeline unit
#define UNITS 24        // 768/32
#define SLOT_ELEMS ((BM + BN) * BKU)   // 16384 elems = 32 KB
#define THREADS 512
#define XPB 2304        // blocks for x-conversion in prep_all

using short8 = __attribute__((ext_vector_type(8))) short;
using f32x4  = __attribute__((ext_vector_type(4))) float;

static __device__ __forceinline__ unsigned short f2bf(float f) {
  union { float f; unsigned int u; } v; v.f = f;
  unsigned int u = v.u;
  unsigned int r = (u + 0x7FFFu + ((u >> 16) & 1u)) >> 16;
  return (unsigned short)r;
}

// ---------------- Fused prep: blocks [0,XPB) convert x -> A (bf16, merged (c,h) K axis);
// blocks [XPB, XPB+1024) normalize weights -> Qt (bf16) + wnT (f32, [48][4096]).
__global__ __launch_bounds__(256)
void prep_all(const float* __restrict__ x,
              const float* __restrict__ width,
              const float* __restrict__ height,
              const float* __restrict__ feat,
              unsigned short* __restrict__ A,
              unsigned short* __restrict__ Qt,
              float* __restrict__ wnT) {
  __shared__ float smw[4][WW];
  int bid = blockIdx.x;
  if (bid < XPB) {
    int t = bid * 256 + threadIdx.x;      // XPB*256 == BB*CC*WW*HH/8 exactly
    int e = t * 8;
    int h0 = e % HH;                      // 8 | 48: the 8 elems share (b,c,w)
    int w = (e / HH) % WW;
    int c = (e / (HH * WW)) % CC;
    int b = e / (HH * WW * CC);
    float4 v0 = *(const float4*)(x + e);
    float4 v1 = *(const float4*)(x + e + 4);
    short8 o;
    o[0] = (short)f2bf(v0.x); o[1] = (short)f2bf(v0.y);
    o[2] = (short)f2bf(v0.z); o[3] = (short)f2bf(v0.w);
    o[4] = (short)f2bf(v1.x); o[5] = (short)f2bf(v1.y);
    o[6] = (short)f2bf(v1.z); o[7] = (short)f2bf(v1.w);
    *(short8*)&A[(size_t)(b * WW + w) * KD + c * HH + h0] = o;
  } else {
    int lane = threadIdx.x & 63;
    int wv = threadIdx.x >> 6;            // wave 0..3
    int nbase = (bid - XPB) * 4;
    int n = nbase + wv;                   // 0..4095
    bool valid = (n < OUTD);
    float hv = (valid && lane < HH) ? height[n * HH + lane] : 0.f;
    float wvv = (valid && lane < WW) ? width[n * WW + lane] : 0.f;
    float hs = hv * hv, wsum = wvv * wvv;
    #pragma unroll
    for (int off = 32; off > 0; off >>= 1) {
      hs += __shfl_xor(hs, off);
      wsum += __shfl_xor(wsum, off);
    }
    float hnorm = rsqrtf(hs + EPSF);
    float wnorm = rsqrtf(wsum + EPSF);
    if (lane < WW) smw[wv][lane] = wvv * wnorm;   // 0 for invalid n
    if (valid) {
      #pragma unroll
      for (int i = lane; i < KD; i += 64) {
        int c = i / HH, h = i % HH;
        Qt[(size_t)n * KD + i] = f2bf(feat[n * CC + c] * height[n * HH + h] * hnorm);
      }
    } else {
      #pragma unroll
      for (int i = lane; i < KD; i += 64) Qt[(size_t)n * KD + i] = 0;
    }
    __syncthreads();
    if (threadIdx.x < WW) {
      int w = threadIdx.x;
      float4 o = make_float4(smw[0][w], smw[1][w], smw[2][w], smw[3][w]);
      *(float4*)&wnT[w * NPAD + nbase] = o;
    }
  }
}

// ---------------- Main GEMM: P = A (6144x768) * Qt^T (768x4096), fused w-reduction epilogue.
// 384x128 tile, 8 waves (4m x 2n), wave tile 96x64. Pipeline units of BK=32, ring of 4
// LDS slots, prefetch depth 3 -> steady-state vmcnt(12). 2 phases x 12 MFMA per unit.
__global__ __launch_bounds__(THREADS, 2)
void gemm_main(const unsigned short* __restrict__ A,   // [6144][768] bf16 bits
               const unsigned short* __restrict__ Qt,  // [4096][768] bf16 bits
               const float* __restrict__ wnT,          // [48][4096]
               const float* __restrict__ bias,         // [4000]
               float* __restrict__ out) {              // [128][4000]
  __shared__ unsigned short S[4 * SLOT_ELEMS];   // 131072 B -> 1 block/CU

  int tid = threadIdx.x;
  int lane = tid & 63;
  int wid = tid >> 6;          // 0..7
  int wm = wid >> 1;           // 0..3 -> 96-row slice of the tile
  int wnh = wid & 1;           // 0..1 -> 64-col half

  // XCD-local mapping: XCD k (= bid&7) owns by in {2k, 2k+1}, sweeps bx.
  // A-share per XCD = 2*576KB = 1.15MB (L2-resident); Qt streams once per XCD.
  int bid = blockIdx.x;        // 0..511
  int xcd = bid & 7;
  int i = bid >> 3;            // 0..63
  int by = xcd * 2 + (i & 1);  // m tile 0..15
  int bx = i >> 1;             // n tile 0..31
  int n0 = bx * BN;
  int m0 = by * BM;

  // ---- staging: per wave 3 A-loads + 1 B-load per unit (each: 16 rows x 32 elems = 1KB).
  // LDS dest linear; global source granule XOR-pre-swizzled: LDS[row][g*8..] holds
  // global[row][(g ^ ((row>>1)&3))*8..]  (granule = 8 elems = 16B, row = 64B).
  int lrow = lane >> 2;              // 0..15 row within chunk
  int g = lane & 3;                  // granule within 32-elem row
  int gsw = (g ^ ((lrow >> 1) & 3)) * 8;
  const unsigned short* gA0 = A + (size_t)(m0 + (wid * 3 + 0) * 16 + lrow) * KD + gsw;
  const unsigned short* gA1 = A + (size_t)(m0 + (wid * 3 + 1) * 16 + lrow) * KD + gsw;
  const unsigned short* gA2 = A + (size_t)(m0 + (wid * 3 + 2) * 16 + lrow) * KD + gsw;
  const unsigned short* gB0 = Qt + (size_t)(n0 + wid * 16 + lrow) * KD + gsw;
  int aD0 = (wid * 3 + 0) * 512;     // elem offsets of chunk bases within a slot
  int aD1 = (wid * 3 + 1) * 512;
  int aD2 = (wid * 3 + 2) * 512;
  int bD  = BM * BKU + wid * 512;

#define SLOTB(u) (((u) & 3) * SLOT_ELEMS)
#define STAGE(u)                                                                  \
  { __builtin_amdgcn_global_load_lds(                                             \
        (const __attribute__((address_space(1))) void*)(gA0 + (u) * BKU),         \
        (__attribute__((address_space(3))) void*)(&S[SLOTB(u) + aD0]), 16, 0, 0); \
    __builtin_amdgcn_global_load_lds(                                             \
        (const __attribute__((address_space(1))) void*)(gA1 + (u) * BKU),         \
        (__attribute__((address_space(3))) void*)(&S[SLOTB(u) + aD1]), 16, 0, 0); \
    __builtin_amdgcn_global_load_lds(                                             \
        (const __attribute__((address_space(1))) void*)(gA2 + (u) * BKU),         \
        (__attribute__((address_space(3))) void*)(&S[SLOTB(u) + aD2]), 16, 0, 0); \
    __builtin_amdgcn_global_load_lds(                                             \
        (const __attribute__((address_space(1))) void*)(gB0 + (u) * BKU),         \
        (__attribute__((address_space(3))) void*)(&S[SLOTB(u) + bD]), 16, 0, 0); }

  // ---- ds_read offsets (elem) with matching swizzle; rows are 32 elems (64B).
  int q16 = lane & 15;
  int hi = lane >> 4;                // 0..3 -> k-granule
  int kq = (q16 >> 1) & 3;
  int aoff = (wm * 96 + q16) * BKU + (hi ^ kq) * 8;             // + mi*512
  int boff = BM * BKU + (wnh * 64 + q16) * BKU + (hi ^ kq) * 8; // + ni*512

  f32x4 acc[6][4] = {};

  STAGE(0); STAGE(1); STAGE(2);      // prologue: 3 units in flight (12 loads/wave)

  #pragma unroll
  for (int u = 0; u < UNITS; ++u) {
    if (u + 3 < UNITS) STAGE(u + 3);           // refill slot (u-1)&3 (freed last unit)
    __builtin_amdgcn_sched_barrier(0);
    if (u <= UNITS - 4)      asm volatile("s_waitcnt vmcnt(12)" ::: "memory");
    else if (u == UNITS - 3) asm volatile("s_waitcnt vmcnt(8)" ::: "memory");
    else if (u == UNITS - 2) asm volatile("s_waitcnt vmcnt(4)" ::: "memory");
    else                     asm volatile("s_waitcnt vmcnt(0)" ::: "memory");
    __builtin_amdgcn_s_barrier();              // unit u staged by all waves
    __builtin_amdgcn_sched_barrier(0);

    const unsigned short* sb = &S[SLOTB(u)];
    short8 af0 = *(const short8*)&sb[aoff];
    short8 af1 = *(const short8*)&sb[aoff + 512];
    short8 af2 = *(const short8*)&sb[aoff + 1024];
    short8 af3 = *(const short8*)&sb[aoff + 1536];
    short8 af4 = *(const short8*)&sb[aoff + 2048];
    short8 af5 = *(const short8*)&sb[aoff + 2560];
    short8 bf0 = *(const short8*)&sb[boff];
    short8 bf1 = *(const short8*)&sb[boff + 512];
    asm volatile("s_waitcnt lgkmcnt(0)" ::: "memory");
    __builtin_amdgcn_sched_barrier(0);
    __builtin_amdgcn_s_setprio(1);
    acc[0][0] = __builtin_amdgcn_mfma_f32_16x16x32_bf16(af0, bf0, acc[0][0], 0, 0, 0);
    acc[1][0] = __builtin_amdgcn_mfma_f32_16x16x32_bf16(af1, bf0, acc[1][0], 0, 0, 0);
    acc[2][0] = __builtin_amdgcn_mfma_f32_16x16x32_bf16(af2, bf0, acc[2][0], 0, 0, 0);
    acc[3][0] = __builtin_amdgcn_mfma_f32_16x16x32_bf16(af3, bf0, acc[3][0], 0, 0, 0);
    acc[4][0] = __builtin_amdgcn_mfma_f32_16x16x32_bf16(af4, bf0, acc[4][0], 0, 0, 0);
    acc[5][0] = __builtin_amdgcn_mfma_f32_16x16x32_bf16(af5, bf0, acc[5][0], 0, 0, 0);
    acc[0][1] = __builtin_amdgcn_mfma_f32_16x16x32_bf16(af0, bf1, acc[0][1], 0, 0, 0);
    acc[1][1] = __builtin_amdgcn_mfma_f32_16x16x32_bf16(af1, bf1, acc[1][1], 0, 0, 0);
    acc[2][1] = __builtin_amdgcn_mfma_f32_16x16x32_bf16(af2, bf1, acc[2][1], 0, 0, 0);
    acc[3][1] = __builtin_amdgcn_mfma_f32_16x16x32_bf16(af3, bf1, acc[3][1], 0, 0, 0);
    acc[4][1] = __builtin_amdgcn_mfma_f32_16x16x32_bf16(af4, bf1, acc[4][1], 0, 0, 0);
    acc[5][1] = __builtin_amdgcn_mfma_f32_16x16x32_bf16(af5, bf1, acc[5][1], 0, 0, 0);
    __builtin_amdgcn_s_setprio(0);
    __builtin_amdgcn_sched_barrier(0);

    short8 bf2 = *(const short8*)&sb[boff + 1024];
    short8 bf3 = *(const short8*)&sb[boff + 1536];
    asm volatile("s_waitcnt lgkmcnt(0)" ::: "memory");
    __builtin_amdgcn_sched_barrier(0);
    __builtin_amdgcn_s_setprio(1);
    acc[0][2] = __builtin_amdgcn_mfma_f32_16x16x32_bf16(af0, bf2, acc[0][2], 0, 0, 0);
    acc[1][2] = __builtin_amdgcn_mfma_f32_16x16x32_bf16(af1, bf2, acc[1][2], 0, 0, 0);
    acc[2][2] = __builtin_amdgcn_mfma_f32_16x16x32_bf16(af2, bf2, acc[2][2], 0, 0, 0);
    acc[3][2] = __builtin_amdgcn_mfma_f32_16x16x32_bf16(af3, bf2, acc[3][2], 0, 0, 0);
    acc[4][2] = __builtin_amdgcn_mfma_f32_16x16x32_bf16(af4, bf2, acc[4][2], 0, 0, 0);
    acc[5][2] = __builtin_amdgcn_mfma_f32_16x16x32_bf16(af5, bf2, acc[5][2], 0, 0, 0);
    acc[0][3] = __builtin_amdgcn_mfma_f32_16x16x32_bf16(af0, bf3, acc[0][3], 0, 0, 0);
    acc[1][3] = __builtin_amdgcn_mfma_f32_16x16x32_bf16(af1, bf3, acc[1][3], 0, 0, 0);
    acc[2][3] = __builtin_amdgcn_mfma_f32_16x16x32_bf16(af2, bf3, acc[2][3], 0, 0, 0);
    acc[3][3] = __builtin_amdgcn_mfma_f32_16x16x32_bf16(af3, bf3, acc[3][3], 0, 0, 0);
    acc[4][3] = __builtin_amdgcn_mfma_f32_16x16x32_bf16(af4, bf3, acc[4][3], 0, 0, 0);
    acc[5][3] = __builtin_amdgcn_mfma_f32_16x16x32_bf16(af5, bf3, acc[5][3], 0, 0, 0);
    __builtin_amdgcn_s_setprio(0);
    __builtin_amdgcn_s_barrier();              // slot u&3 fully consumed
    __builtin_amdgcn_sched_barrier(0);
  }

  // ---- Epilogue: y[b,n] = sum_w wnT[w][n] * P[(b,w),n] + bias[n]
  // wave rows: r = wm*96 + mi*16 + hi*4 + rr; batch = by*8 + wm*2 + (mi>=3); w = (mi%3)*16+hi*4+rr.
  int b0 = by * 8 + wm * 2;
  #pragma unroll
  for (int ni = 0; ni < 4; ++ni) {
    int ng = n0 + wnh * 64 + ni * 16 + q16;
    float s0 = 0.f, s1 = 0.f;
    #pragma unroll
    for (int mi = 0; mi < 3; ++mi) {
      int wbase = mi * 16 + hi * 4;
      f32x4 va = acc[mi][ni];
      f32x4 vb = acc[mi + 3][ni];
      #pragma unroll
      for (int r = 0; r < 4; ++r) {
        float t = wnT[(wbase + r) * NPAD + ng];
        s0 += t * va[r];
        s1 += t * vb[r];
      }
    }
    s0 += __shfl_xor(s0, 16); s0 += __shfl_xor(s0, 32);
    s1 += __shfl_xor(s1, 16); s1 += __shfl_xor(s1, 32);
    if (hi == 0 && ng < OUTD) {
      float bv = bias[ng];
      out[(size_t)b0 * OUTD + ng] = s0 + bv;
      out[(size_t)(b0 + 1) * OUTD + ng] = s1 + bv;
    }
  }
#undef STAGE
#undef SLOTB
}

extern "C" void kernel_launch(void* const* d_in, const int* in_sizes, int n_in,
                              void* d_out, int out_size, void* d_ws, size_t ws_size,
                              hipStream_t stream) {
  const float* x      = (const float*)d_in[0];
  const float* width  = (const float*)d_in[1];
  const float* height = (const float*)d_in[2];
  const float* feat   = (const float*)d_in[3];
  const float* bias   = (const float*)d_in[4];
  float* out = (float*)d_out;

  char* ws = (char*)d_ws;
  unsigned short* A  = (unsigned short*)ws;                        // 6144*768*2 = 9,437,184
  unsigned short* Qt = (unsigned short*)(ws + 9437184);            // 4096*768*2 = 6,291,456
  float* wnT         = (float*)(ws + 9437184 + 6291456);           // 48*4096*4  =   786,432

  prep_all<<<dim3(XPB + NPAD / 4), dim3(256), 0, stream>>>(x, width, height, feat, A, Qt, wnT);
  gemm_main<<<dim3(512), dim3(THREADS), 0, stream>>>(A, Qt, wnT, bias, out);
}

// Round 5
// 53.537 us; speedup vs baseline: 1.4633x; 1.0627x over previous
//
#include <hip/hip_runtime.h>
#include <stdint.h>

#define OUTD 4000
#define NPAD 4096
#define CC 16
#define WW 48
#define HH 48
#define BB 128
#define KD 768          // C*H contraction depth
#define MD 6144         // B*W rows
#define EPSF 1e-6f

#define BM 384          // 8 batches * 48 w
#define BN 128
#define BKU 32          // K elems per pipeline unit
#define UNITS 24        // 768/32
#define SLOT_ELEMS ((BM + BN) * BKU)   // 16384 elems = 32 KB
#define THREADS 512
#define XPB 2304        // blocks for x-conversion in prep_all

using short8 = __attribute__((ext_vector_type(8))) short;
using f32x4  = __attribute__((ext_vector_type(4))) float;

static __device__ __forceinline__ unsigned short f2bf(float f) {
  union { float f; unsigned int u; } v; v.f = f;
  unsigned int u = v.u;
  unsigned int r = (u + 0x7FFFu + ((u >> 16) & 1u)) >> 16;
  return (unsigned short)r;
}

// ---------------- Fused prep: blocks [0,XPB) convert x -> A (bf16, merged (c,h) K axis);
// blocks [XPB, XPB+1024) normalize weights -> Qt (bf16) + wnT (f32, [48][4096]).
__global__ __launch_bounds__(256)
void prep_all(const float* __restrict__ x,
              const float* __restrict__ width,
              const float* __restrict__ height,
              const float* __restrict__ feat,
              unsigned short* __restrict__ A,
              unsigned short* __restrict__ Qt,
              float* __restrict__ wnT) {
  __shared__ float smw[4][WW];
  int bid = blockIdx.x;
  if (bid < XPB) {
    int t = bid * 256 + threadIdx.x;      // XPB*256 == BB*CC*WW*HH/8 exactly
    int e = t * 8;
    int h0 = e % HH;                      // 8 | 48: the 8 elems share (b,c,w)
    int w = (e / HH) % WW;
    int c = (e / (HH * WW)) % CC;
    int b = e / (HH * WW * CC);
    float4 v0 = *(const float4*)(x + e);
    float4 v1 = *(const float4*)(x + e + 4);
    short8 o;
    o[0] = (short)f2bf(v0.x); o[1] = (short)f2bf(v0.y);
    o[2] = (short)f2bf(v0.z); o[3] = (short)f2bf(v0.w);
    o[4] = (short)f2bf(v1.x); o[5] = (short)f2bf(v1.y);
    o[6] = (short)f2bf(v1.z); o[7] = (short)f2bf(v1.w);
    *(short8*)&A[(size_t)(b * WW + w) * KD + c * HH + h0] = o;
  } else {
    int lane = threadIdx.x & 63;
    int wv = threadIdx.x >> 6;            // wave 0..3
    int nbase = (bid - XPB) * 4;
    int n = nbase + wv;                   // 0..4095
    bool valid = (n < OUTD);
    float hv = (valid && lane < HH) ? height[n * HH + lane] : 0.f;
    float wvv = (valid && lane < WW) ? width[n * WW + lane] : 0.f;
    float hs = hv * hv, wsum = wvv * wvv;
    #pragma unroll
    for (int off = 32; off > 0; off >>= 1) {
      hs += __shfl_xor(hs, off);
      wsum += __shfl_xor(wsum, off);
    }
    float hnorm = rsqrtf(hs + EPSF);
    float wnorm = rsqrtf(wsum + EPSF);
    if (lane < WW) smw[wv][lane] = wvv * wnorm;   // 0 for invalid n
    if (valid) {
      #pragma unroll
      for (int i = lane; i < KD; i += 64) {
        int c = i / HH, h = i % HH;
        Qt[(size_t)n * KD + i] = f2bf(feat[n * CC + c] * height[n * HH + h] * hnorm);
      }
    } else {
      #pragma unroll
      for (int i = lane; i < KD; i += 64) Qt[(size_t)n * KD + i] = 0;
    }
    __syncthreads();
    if (threadIdx.x < WW) {
      int w = threadIdx.x;
      float4 o = make_float4(smw[0][w], smw[1][w], smw[2][w], smw[3][w]);
      *(float4*)&wnT[w * NPAD + nbase] = o;
    }
  }
}

// ---------------- Main GEMM: P = A (6144x768) * Qt^T (768x4096), fused w-reduction epilogue.
// 384x128 tile, 8 waves (4m x 2n), wave tile 96x64. Ring of 4 LDS slots, staging depth 3.
// ds_reads software-pipelined ONE UNIT AHEAD: per unit {STAGE(u+3); vmcnt(8); barrier;
// ds_read(u+1)->alt regs; 24 MFMA on current regs}. Reads complete under the MFMA cluster.
__global__ __launch_bounds__(THREADS, 2)
void gemm_main(const unsigned short* __restrict__ A,   // [6144][768] bf16 bits
               const unsigned short* __restrict__ Qt,  // [4096][768] bf16 bits
               const float* __restrict__ wnT,          // [48][4096]
               const float* __restrict__ bias,         // [4000]
               float* __restrict__ out) {              // [128][4000]
  __shared__ unsigned short S[4 * SLOT_ELEMS];   // 131072 B -> 1 block/CU

  int tid = threadIdx.x;
  int lane = tid & 63;
  int wid = tid >> 6;          // 0..7
  int wm = wid >> 1;           // 0..3 -> 96-row slice of the tile
  int wnh = wid & 1;           // 0..1 -> 64-col half

  // XCD-local mapping: XCD k (= bid&7) owns by in {2k, 2k+1}, sweeps bx.
  int bid = blockIdx.x;        // 0..511
  int xcd = bid & 7;
  int i = bid >> 3;            // 0..63
  int by = xcd * 2 + (i & 1);  // m tile 0..15
  int bx = i >> 1;             // n tile 0..31
  int n0 = bx * BN;
  int m0 = by * BM;

  // ---- staging: per wave 3 A-loads + 1 B-load per unit (each: 16 rows x 32 elems = 1KB).
  // LDS dest linear; global source granule XOR-pre-swizzled: LDS[row][g*8..] holds
  // global[row][(g ^ ((row>>1)&3))*8..]  (granule = 8 elems = 16B, row = 64B).
  int lrow = lane >> 2;              // 0..15 row within chunk
  int g = lane & 3;                  // granule within 32-elem row
  int gsw = (g ^ ((lrow >> 1) & 3)) * 8;
  const unsigned short* gA0 = A + (size_t)(m0 + (wid * 3 + 0) * 16 + lrow) * KD + gsw;
  const unsigned short* gA1 = A + (size_t)(m0 + (wid * 3 + 1) * 16 + lrow) * KD + gsw;
  const unsigned short* gA2 = A + (size_t)(m0 + (wid * 3 + 2) * 16 + lrow) * KD + gsw;
  const unsigned short* gB0 = Qt + (size_t)(n0 + wid * 16 + lrow) * KD + gsw;
  int aD0 = (wid * 3 + 0) * 512;     // elem offsets of chunk bases within a slot
  int aD1 = (wid * 3 + 1) * 512;
  int aD2 = (wid * 3 + 2) * 512;
  int bD  = BM * BKU + wid * 512;

#define SLOTB(u) (((u) & 3) * SLOT_ELEMS)
#define STAGE(u)                                                                  \
  { __builtin_amdgcn_global_load_lds(                                             \
        (const __attribute__((address_space(1))) void*)(gA0 + (u) * BKU),         \
        (__attribute__((address_space(3))) void*)(&S[SLOTB(u) + aD0]), 16, 0, 0); \
    __builtin_amdgcn_global_load_lds(                                             \
        (const __attribute__((address_space(1))) void*)(gA1 + (u) * BKU),         \
        (__attribute__((address_space(3))) void*)(&S[SLOTB(u) + aD1]), 16, 0, 0); \
    __builtin_amdgcn_global_load_lds(                                             \
        (const __attribute__((address_space(1))) void*)(gA2 + (u) * BKU),         \
        (__attribute__((address_space(3))) void*)(&S[SLOTB(u) + aD2]), 16, 0, 0); \
    __builtin_amdgcn_global_load_lds(                                             \
        (const __attribute__((address_space(1))) void*)(gB0 + (u) * BKU),         \
        (__attribute__((address_space(3))) void*)(&S[SLOTB(u) + bD]), 16, 0, 0); }

  // ---- ds_read offsets (elem) with matching swizzle; rows are 32 elems (64B).
  int q16 = lane & 15;
  int hi = lane >> 4;                // 0..3 -> k-granule
  int kq = (q16 >> 1) & 3;
  int aoff = (wm * 96 + q16) * BKU + (hi ^ kq) * 8;             // + mi*512
  int boff = BM * BKU + (wnh * 64 + q16) * BKU + (hi ^ kq) * 8; // + ni*512

  f32x4 acc[6][4] = {};
  short8 afr[2][6];
  short8 bfr[2][4];

#define DSREAD(set, u)                                          \
  { const unsigned short* sb = &S[SLOTB(u)];                    \
    afr[set][0] = *(const short8*)&sb[aoff];                    \
    afr[set][1] = *(const short8*)&sb[aoff + 512];              \
    afr[set][2] = *(const short8*)&sb[aoff + 1024];             \
    afr[set][3] = *(const short8*)&sb[aoff + 1536];             \
    afr[set][4] = *(const short8*)&sb[aoff + 2048];             \
    afr[set][5] = *(const short8*)&sb[aoff + 2560];             \
    bfr[set][0] = *(const short8*)&sb[boff];                    \
    bfr[set][1] = *(const short8*)&sb[boff + 512];              \
    bfr[set][2] = *(const short8*)&sb[boff + 1024];             \
    bfr[set][3] = *(const short8*)&sb[boff + 1536]; }

  // Prologue: 3 units in flight; read unit 0 into reg set 0.
  STAGE(0); STAGE(1); STAGE(2);
  asm volatile("s_waitcnt vmcnt(8)" ::: "memory");
  __builtin_amdgcn_s_barrier();
  __builtin_amdgcn_sched_barrier(0);
  DSREAD(0, 0);
  __builtin_amdgcn_sched_barrier(0);

  #pragma unroll
  for (int u = 0; u < UNITS; ++u) {
    if (u + 3 < UNITS) STAGE(u + 3);           // refill slot (u-1)&3
    if (u + 1 < UNITS) {
      // own-wave wait: unit u+1's 4 loads landed
      if (u <= UNITS - 4)      asm volatile("s_waitcnt vmcnt(8)" ::: "memory");
      else if (u == UNITS - 3) asm volatile("s_waitcnt vmcnt(4)" ::: "memory");
      else                     asm volatile("s_waitcnt vmcnt(0)" ::: "memory");
      __builtin_amdgcn_s_barrier();            // all waves' u+1 loads landed;
                                               // also: all waves done reading slot u-1
      __builtin_amdgcn_sched_barrier(0);
      DSREAD((u + 1) & 1, u + 1);              // overlaps with MFMA(u) below
      __builtin_amdgcn_sched_barrier(0);
    }
    const int cs = u & 1;
    __builtin_amdgcn_s_setprio(1);
    #pragma unroll
    for (int ni = 0; ni < 4; ++ni)
      #pragma unroll
      for (int mi = 0; mi < 6; ++mi)
        acc[mi][ni] = __builtin_amdgcn_mfma_f32_16x16x32_bf16(afr[cs][mi], bfr[cs][ni], acc[mi][ni], 0, 0, 0);
    __builtin_amdgcn_s_setprio(0);
    __builtin_amdgcn_sched_barrier(0);
  }

  // ---- Epilogue: y[b,n] = sum_w wnT[w][n] * P[(b,w),n] + bias[n]
  // wave rows: r = wm*96 + mi*16 + hi*4 + rr; batch = by*8 + wm*2 + (mi>=3); w = (mi%3)*16+hi*4+rr.
  int b0 = by * 8 + wm * 2;
  #pragma unroll
  for (int ni = 0; ni < 4; ++ni) {
    int ng = n0 + wnh * 64 + ni * 16 + q16;
    float s0 = 0.f, s1 = 0.f;
    #pragma unroll
    for (int mi = 0; mi < 3; ++mi) {
      int wbase = mi * 16 + hi * 4;
      f32x4 va = acc[mi][ni];
      f32x4 vb = acc[mi + 3][ni];
      #pragma unroll
      for (int r = 0; r < 4; ++r) {
        float t = wnT[(wbase + r) * NPAD + ng];
        s0 += t * va[r];
        s1 += t * vb[r];
      }
    }
    s0 += __shfl_xor(s0, 16); s0 += __shfl_xor(s0, 32);
    s1 += __shfl_xor(s1, 16); s1 += __shfl_xor(s1, 32);
    if (hi == 0 && ng < OUTD) {
      float bv = bias[ng];
      out[(size_t)b0 * OUTD + ng] = s0 + bv;
      out[(size_t)(b0 + 1) * OUTD + ng] = s1 + bv;
    }
  }
#undef STAGE
#undef SLOTB
#undef DSREAD
}

extern "C" void kernel_launch(void* const* d_in, const int* in_sizes, int n_in,
                              void* d_out, int out_size, void* d_ws, size_t ws_size,
                              hipStream_t stream) {
  const float* x      = (const float*)d_in[0];
  const float* width  = (const float*)d_in[1];
  const float* height = (const float*)d_in[2];
  const float* feat   = (const float*)d_in[3];
  const float* bias   = (const float*)d_in[4];
  float* out = (float*)d_out;

  char* ws = (char*)d_ws;
  unsigned short* A  = (unsigned short*)ws;                        // 6144*768*2 = 9,437,184
  unsigned short* Qt = (unsigned short*)(ws + 9437184);            // 4096*768*2 = 6,291,456
  float* wnT         = (float*)(ws + 9437184 + 6291456);           // 48*4096*4  =   786,432

  prep_all<<<dim3(XPB + NPAD / 4), dim3(256), 0, stream>>>(x, width, height, feat, A, Qt, wnT);
  gemm_main<<<dim3(512), dim3(THREADS), 0, stream>>>(A, Qt, wnT, bias, out);
}